// Round 1
// 270.779 us; speedup vs baseline: 1.0196x; 1.0196x over previous
//
#include <hip/hip_runtime.h>

#define SSIM_H 512
#define SSIM_W 512
#define PLANES 96
#define TILE 64
#define GRID_X (SSIM_W / TILE)
#define GRID_Y (SSIM_H / TILE)
#define TOTAL_BLOCKS (GRID_X * GRID_Y * PLANES)  // 6144
#define N_TOTAL 25165824.0

typedef _Float16 half4v __attribute__((ext_vector_type(4)));
typedef _Float16 half8v __attribute__((ext_vector_type(8)));
typedef float float4v __attribute__((ext_vector_type(4)));

struct __align__(16) d2 { double x, y; };

// Gaussian tap k (0..10), sigma=1.5: exp(-(k-5)^2/4.5) / 3.759233
__device__ __forceinline__ float gwf(int k) {
  const float d = (float)(k - 5);
  return __expf(-d * d / 4.5f) * 0.26601171702936207f;
}

// Both conv passes as mfma_f32_16x16x32_f16 against a banded weight matrix.
// Weight fragment value = w[8q + j - (lane&15)]; serves as stage-1 B
// (B[k][n]=w[k-n]) and stage-2 A (A[i][kk]=w[kk-i]) with identical registers.
//
// Latency restructure vs previous version:
//  * Phase A issues ALL 20 dwordx4 global loads (5 row-groups) into
//    xf[5][8]/yf[5][8] before any convert/MFMA -> one HBM round trip
//    instead of five serialized ones. Interior blocks (x,y in [1,6])
//    take a branch-free path.
//  * Stage 2 is wave-private: wave wv consumes exactly the 16-column
//    Hs slab it produced in stage 1 (loop over row-bands rb instead of
//    col-groups). The inter-stage __syncthreads() is replaced by a
//    wave-local s_waitcnt lgkmcnt(0) -> no convoying, no full
//    vmcnt(0)+lgkmcnt(0) barrier drain.
//  * All 40 stage-2 ds_read_b64 are issued before the first stage-2 MFMA.
//
// H planes stored column-major [plane][col 64][row 84(pad)] f16. Stride 84
// halves = 42 dwords == 10 mod 32 -> conflict-free (measured 0 conflicts).
__global__ __launch_bounds__(256, 3)
void ssim_l1_kernel(const float* __restrict__ pred,
                    const float* __restrict__ targ,
                    double* __restrict__ partials) {
  __shared__ _Float16 Hs[5][64][84];  // 53,760 B -> 3 blocks/CU
  __shared__ float red[2][4];

  const int tid = (int)threadIdx.x;
  const int wv = tid >> 6;    // wave: owns col-group wv in BOTH stages
  const int lane = tid & 63;
  const int q = lane >> 4;    // quad
  const int m = lane & 15;

  const int tr0 = (int)blockIdx.y * TILE;
  const int tc0 = (int)blockIdx.x * TILE;
  const size_t pbase = (size_t)blockIdx.z * (SSIM_H * SSIM_W);
  const float* __restrict__ xp = pred + pbase;
  const float* __restrict__ yp = targ + pbase;

  // Per-lane banded weight fragment.
  half8v wf;
#pragma unroll
  for (int j = 0; j < 8; ++j) {
    const int k = 8 * q + j - m;
    const float v = (k >= 0 && k <= 10) ? gwf(k) : 0.0f;
    wf[j] = (_Float16)v;
  }

  const int cw = tc0 + 16 * wv;      // wave's output col-group (global)
  const int cbase = cw - 5 + 8 * q;  // first of 8 raw cols for this lane

  // ---------------- Phase A: issue ALL stage-1 global loads ----------------
  float xf[5][8], yf[5][8];
  const bool interior = (tr0 >= 5) && (tr0 + 74 < SSIM_H) &&
                        (tc0 >= 5) && (tc0 + 74 < SSIM_W);
  if (interior) {
    // rows tr0-5 .. tr0+74 and cols cbase..cbase+7 all in range, for all
    // lanes: straight-line, 20 x dwordx4, no guards.
#pragma unroll
    for (int rg = 0; rg < 5; ++rg) {
      const int grow = tr0 - 5 + rg * 16 + m;
      const float* __restrict__ xr = xp + (size_t)grow * SSIM_W;
      const float* __restrict__ yr = yp + (size_t)grow * SSIM_W;
      float4 a0, a1, b0, b1;
      __builtin_memcpy(&a0, xr + cbase, 16);
      __builtin_memcpy(&a1, xr + cbase + 4, 16);
      __builtin_memcpy(&b0, yr + cbase, 16);
      __builtin_memcpy(&b1, yr + cbase + 4, 16);
      xf[rg][0] = a0.x; xf[rg][1] = a0.y; xf[rg][2] = a0.z; xf[rg][3] = a0.w;
      xf[rg][4] = a1.x; xf[rg][5] = a1.y; xf[rg][6] = a1.z; xf[rg][7] = a1.w;
      yf[rg][0] = b0.x; yf[rg][1] = b0.y; yf[rg][2] = b0.z; yf[rg][3] = b0.w;
      yf[rg][4] = b1.x; yf[rg][5] = b1.y; yf[rg][6] = b1.z; yf[rg][7] = b1.w;
    }
  } else {
    const bool cfast = (cbase >= 0) && (cbase + 7 < SSIM_W);
#pragma unroll
    for (int rg = 0; rg < 5; ++rg) {
      const int grow = tr0 - 5 + rg * 16 + m;
      if ((unsigned)grow < (unsigned)SSIM_H) {
        const float* __restrict__ xr = xp + (size_t)grow * SSIM_W;
        const float* __restrict__ yr = yp + (size_t)grow * SSIM_W;
        if (cfast) {
          float4 a0, a1, b0, b1;
          __builtin_memcpy(&a0, xr + cbase, 16);
          __builtin_memcpy(&a1, xr + cbase + 4, 16);
          __builtin_memcpy(&b0, yr + cbase, 16);
          __builtin_memcpy(&b1, yr + cbase + 4, 16);
          xf[rg][0] = a0.x; xf[rg][1] = a0.y; xf[rg][2] = a0.z; xf[rg][3] = a0.w;
          xf[rg][4] = a1.x; xf[rg][5] = a1.y; xf[rg][6] = a1.z; xf[rg][7] = a1.w;
          yf[rg][0] = b0.x; yf[rg][1] = b0.y; yf[rg][2] = b0.z; yf[rg][3] = b0.w;
          yf[rg][4] = b1.x; yf[rg][5] = b1.y; yf[rg][6] = b1.z; yf[rg][7] = b1.w;
        } else {
#pragma unroll
          for (int j = 0; j < 8; ++j) {
            const int c = cbase + j;
            const bool ok = (unsigned)c < (unsigned)SSIM_W;
            xf[rg][j] = ok ? xr[c] : 0.0f;
            yf[rg][j] = ok ? yr[c] : 0.0f;
          }
        }
      } else {
#pragma unroll
        for (int j = 0; j < 8; ++j) { xf[rg][j] = 0.0f; yf[rg][j] = 0.0f; }
      }
    }
  }

  // ---------------- Phase B: L1 + convert + horizontal conv -> Hs ----------
  float l1 = 0.0f;
#pragma unroll
  for (int rg = 0; rg < 5; ++rg) {
    // Exact fp32 L1 on core pixels, counted exactly once:
    // core rows hr in [5,69), core cols k = 8q+j in [5,21).
    const int hr = rg * 16 + m;
    if (hr >= 5 && hr < 69) {
#pragma unroll
      for (int j = 0; j < 8; ++j) {
        const int k = 8 * q + j;
        if (k >= 5 && k < 21) l1 += fabsf(xf[rg][j] - yf[rg][j]);
      }
    }

    half8v ax, ay, axx, ayy, axy;
#pragma unroll
    for (int j = 0; j < 8; ++j) {
      const float x = xf[rg][j], y = yf[rg][j];
      ax[j]  = (_Float16)x;
      ay[j]  = (_Float16)y;
      axx[j] = (_Float16)(x * x);
      ayy[j] = (_Float16)(y * y);
      axy[j] = (_Float16)(x * y);
    }
    const float4v z = {0.0f, 0.0f, 0.0f, 0.0f};
    float4v c0 = __builtin_amdgcn_mfma_f32_16x16x32_f16(ax,  wf, z, 0, 0, 0);
    float4v c1 = __builtin_amdgcn_mfma_f32_16x16x32_f16(ay,  wf, z, 0, 0, 0);
    float4v c2 = __builtin_amdgcn_mfma_f32_16x16x32_f16(axx, wf, z, 0, 0, 0);
    float4v c3 = __builtin_amdgcn_mfma_f32_16x16x32_f16(ayy, wf, z, 0, 0, 0);
    float4v c4 = __builtin_amdgcn_mfma_f32_16x16x32_f16(axy, wf, z, 0, 0, 0);

    // C layout: col=lane&15, row=4q+reg (rows contiguous -> one b64/plane).
    const int hcol = 16 * wv + m;
    const int hrow = rg * 16 + 4 * q;
    half4v h;
    h[0] = (_Float16)c0[0]; h[1] = (_Float16)c0[1];
    h[2] = (_Float16)c0[2]; h[3] = (_Float16)c0[3];
    *(half4v*)&Hs[0][hcol][hrow] = h;
    h[0] = (_Float16)c1[0]; h[1] = (_Float16)c1[1];
    h[2] = (_Float16)c1[2]; h[3] = (_Float16)c1[3];
    *(half4v*)&Hs[1][hcol][hrow] = h;
    h[0] = (_Float16)c2[0]; h[1] = (_Float16)c2[1];
    h[2] = (_Float16)c2[2]; h[3] = (_Float16)c2[3];
    *(half4v*)&Hs[2][hcol][hrow] = h;
    h[0] = (_Float16)c3[0]; h[1] = (_Float16)c3[1];
    h[2] = (_Float16)c3[2]; h[3] = (_Float16)c3[3];
    *(half4v*)&Hs[3][hcol][hrow] = h;
    h[0] = (_Float16)c4[0]; h[1] = (_Float16)c4[1];
    h[2] = (_Float16)c4[2]; h[3] = (_Float16)c4[3];
    *(half4v*)&Hs[4][hcol][hrow] = h;
  }

  // Wave-private LDS dependency: wait for THIS wave's ds_writes only.
  // (Stage 2 below reads only the column slab this wave wrote; no
  // cross-wave traffic, so no __syncthreads needed.)
  asm volatile("s_waitcnt lgkmcnt(0)" ::: "memory");

  // ---------------- Stage 2: vertical conv + SSIM (wave-private) ----------
  float ssim = 0.0f;
  {
    const int hcol = 16 * wv + m;  // B-frag col n = lane&15, own slab
    // Issue all 40 ds_read_b64 before any stage-2 MFMA.
    half8v bfr[4][5];
#pragma unroll
    for (int rb = 0; rb < 4; ++rb) {
      const int hrow = 16 * rb + 8 * q;  // window row base (band = rb)
#pragma unroll
      for (int p = 0; p < 5; ++p) {
        const _Float16* hp = &Hs[p][hcol][hrow];
        half4v lo = *(const half4v*)hp;
        half4v hi = *(const half4v*)(hp + 4);
        bfr[rb][p] = __builtin_shufflevector(lo, hi, 0, 1, 2, 3, 4, 5, 6, 7);
      }
    }
    const float C1v = 1.0e-4f, C2v = 9.0e-4f;
#pragma unroll
    for (int rb = 0; rb < 4; ++rb) {
      const float4v z = {0.0f, 0.0f, 0.0f, 0.0f};
      float4v acc[5];
#pragma unroll
      for (int p = 0; p < 5; ++p)
        acc[p] = __builtin_amdgcn_mfma_f32_16x16x32_f16(wf, bfr[rb][p], z,
                                                        0, 0, 0);
#pragma unroll
      for (int r = 0; r < 4; ++r) {
        const float mu1 = acc[0][r], mu2 = acc[1][r];
        const float exx = acc[2][r], eyy = acc[3][r], exy = acc[4][r];
        const float m11 = mu1 * mu1, m22 = mu2 * mu2, m12 = mu1 * mu2;
        const float num = (2.0f * m12 + C1v) * (2.0f * (exy - m12) + C2v);
        const float den = (m11 + m22 + C1v) *
                          ((exx - m11) + (eyy - m22) + C2v);
        ssim += num / den;
      }
    }
  }

  // ---- Reduction: wave shuffle -> LDS -> block -> private partial slot ----
  float v0 = l1, v1 = ssim;
#pragma unroll
  for (int off = 32; off > 0; off >>= 1) {
    v0 += __shfl_down(v0, off, 64);
    v1 += __shfl_down(v1, off, 64);
  }
  if (lane == 0) { red[0][wv] = v0; red[1][wv] = v1; }
  __syncthreads();
  if (tid == 0) {
    d2 s;
    s.x = (double)red[0][0] + (double)red[0][1] +
          (double)red[0][2] + (double)red[0][3];
    s.y = (double)red[1][0] + (double)red[1][1] +
          (double)red[1][2] + (double)red[1][3];
    const int bid = ((int)blockIdx.z * GRID_Y + (int)blockIdx.y) * GRID_X +
                    (int)blockIdx.x;
    *(d2*)(partials + 2 * bid) = s;
  }
}

__global__ __launch_bounds__(256)
void finalize_kernel(const double* __restrict__ partials,
                     float* __restrict__ out) {
  __shared__ double red[2][4];
  const int tid = (int)threadIdx.x;
  double L = 0.0, S = 0.0;
  for (int i = tid; i < TOTAL_BLOCKS; i += 256) {
    const d2 v = *(const d2*)(partials + 2 * i);
    L += v.x;
    S += v.y;
  }
#pragma unroll
  for (int off = 32; off > 0; off >>= 1) {
    L += __shfl_down(L, off, 64);
    S += __shfl_down(S, off, 64);
  }
  const int lane = tid & 63, wid = tid >> 6;
  if (lane == 0) { red[0][wid] = L; red[1][wid] = S; }
  __syncthreads();
  if (tid == 0) {
    const double Ls = red[0][0] + red[0][1] + red[0][2] + red[0][3];
    const double Ss = red[1][0] + red[1][1] + red[1][2] + red[1][3];
    const double invN = 1.0 / N_TOTAL;
    out[0] = (float)(0.84 * (Ls * invN) + 0.16 * (1.0 - Ss * invN));
  }
}

extern "C" void kernel_launch(void* const* d_in, const int* in_sizes, int n_in,
                              void* d_out, int out_size, void* d_ws, size_t ws_size,
                              hipStream_t stream) {
  const float* pred = (const float*)d_in[0];
  const float* targ = (const float*)d_in[1];
  float* out = (float*)d_out;
  double* partials = (double*)d_ws;  // 6144 * 2 doubles = 96 KB

  dim3 grid(GRID_X, GRID_Y, PLANES);  // (8, 8, 96)
  ssim_l1_kernel<<<grid, 256, 0, stream>>>(pred, targ, partials);
  finalize_kernel<<<1, 256, 0, stream>>>(partials, out);
}

// Round 2
// 269.645 us; speedup vs baseline: 1.0239x; 1.0042x over previous
//
#include <hip/hip_runtime.h>

#define SSIM_H 512
#define SSIM_W 512
#define PLANES 96
#define TILE 64
#define GRID_X (SSIM_W / TILE)
#define GRID_Y (SSIM_H / TILE)
#define TOTAL_BLOCKS (GRID_X * GRID_Y * PLANES)  // 6144
#define N_TOTAL 25165824.0

typedef _Float16 half4v __attribute__((ext_vector_type(4)));
typedef _Float16 half8v __attribute__((ext_vector_type(8)));
typedef float float4v __attribute__((ext_vector_type(4)));

struct __align__(16) d2 { double x, y; };

// Gaussian tap k (0..10), sigma=1.5: exp(-(k-5)^2/4.5) / 3.759233
__device__ __forceinline__ float gwf(int k) {
  const float d = (float)(k - 5);
  return __expf(-d * d / 4.5f) * 0.26601171702936207f;
}

// Both conv passes as mfma_f32_16x16x32_f16 against a banded weight matrix.
// Weight fragment value = w[8q + j - (lane&15)]; serves as stage-1 B
// (B[k][n]=w[k-n]) and stage-2 A (A[i][kk]=w[kk-i]) with identical registers.
//
// Round-2 change: Round 1's prefetch was silently re-sunk by the machine
// scheduler (VGPR stayed 68 -> xf/yf never lived across the phases). This
// version pins the phase boundary with sched_barrier(0) so all 20
// global_load_dwordx4 per lane ISSUE before any convert/MFMA executes and
// their results are allocated across the barrier. Expect VGPR ~150.
//
// H planes stored column-major [plane][col 64][row 84(pad)] f16. Stride 84
// halves = 42 dwords == 10 mod 32 -> conflict-free (measured 0 conflicts).
__global__ __launch_bounds__(256, 3)
void ssim_l1_kernel(const float* __restrict__ pred,
                    const float* __restrict__ targ,
                    double* __restrict__ partials) {
  __shared__ _Float16 Hs[5][64][84];  // 53,760 B -> 3 blocks/CU
  __shared__ float red[2][4];

  const int tid = (int)threadIdx.x;
  const int wv = tid >> 6;    // wave: owns col-group wv in BOTH stages
  const int lane = tid & 63;
  const int q = lane >> 4;    // quad
  const int m = lane & 15;

  const int tr0 = (int)blockIdx.y * TILE;
  const int tc0 = (int)blockIdx.x * TILE;
  const size_t pbase = (size_t)blockIdx.z * (SSIM_H * SSIM_W);
  const float* __restrict__ xp = pred + pbase;
  const float* __restrict__ yp = targ + pbase;

  // Per-lane banded weight fragment.
  half8v wf;
#pragma unroll
  for (int j = 0; j < 8; ++j) {
    const int k = 8 * q + j - m;
    const float v = (k >= 0 && k <= 10) ? gwf(k) : 0.0f;
    wf[j] = (_Float16)v;
  }

  const int cw = tc0 + 16 * wv;      // wave's output col-group (global)
  const int cbase = cw - 5 + 8 * q;  // first of 8 raw cols for this lane

  // ---------------- Phase A: issue ALL stage-1 global loads ----------------
  float xf[5][8], yf[5][8];
  const bool interior = (tr0 >= 5) && (tr0 + 74 < SSIM_H) &&
                        (tc0 >= 5) && (tc0 + 74 < SSIM_W);
  if (interior) {
    // rows tr0-5 .. tr0+74 and cols cbase..cbase+7 all in range, for all
    // lanes: straight-line, 20 x dwordx4, no guards.
#pragma unroll
    for (int rg = 0; rg < 5; ++rg) {
      const int grow = tr0 - 5 + rg * 16 + m;
      const float* __restrict__ xr = xp + (size_t)grow * SSIM_W;
      const float* __restrict__ yr = yp + (size_t)grow * SSIM_W;
      float4 a0, a1, b0, b1;
      __builtin_memcpy(&a0, xr + cbase, 16);
      __builtin_memcpy(&a1, xr + cbase + 4, 16);
      __builtin_memcpy(&b0, yr + cbase, 16);
      __builtin_memcpy(&b1, yr + cbase + 4, 16);
      xf[rg][0] = a0.x; xf[rg][1] = a0.y; xf[rg][2] = a0.z; xf[rg][3] = a0.w;
      xf[rg][4] = a1.x; xf[rg][5] = a1.y; xf[rg][6] = a1.z; xf[rg][7] = a1.w;
      yf[rg][0] = b0.x; yf[rg][1] = b0.y; yf[rg][2] = b0.z; yf[rg][3] = b0.w;
      yf[rg][4] = b1.x; yf[rg][5] = b1.y; yf[rg][6] = b1.z; yf[rg][7] = b1.w;
    }
  } else {
    const bool cfast = (cbase >= 0) && (cbase + 7 < SSIM_W);
#pragma unroll
    for (int rg = 0; rg < 5; ++rg) {
      const int grow = tr0 - 5 + rg * 16 + m;
      if ((unsigned)grow < (unsigned)SSIM_H) {
        const float* __restrict__ xr = xp + (size_t)grow * SSIM_W;
        const float* __restrict__ yr = yp + (size_t)grow * SSIM_W;
        if (cfast) {
          float4 a0, a1, b0, b1;
          __builtin_memcpy(&a0, xr + cbase, 16);
          __builtin_memcpy(&a1, xr + cbase + 4, 16);
          __builtin_memcpy(&b0, yr + cbase, 16);
          __builtin_memcpy(&b1, yr + cbase + 4, 16);
          xf[rg][0] = a0.x; xf[rg][1] = a0.y; xf[rg][2] = a0.z; xf[rg][3] = a0.w;
          xf[rg][4] = a1.x; xf[rg][5] = a1.y; xf[rg][6] = a1.z; xf[rg][7] = a1.w;
          yf[rg][0] = b0.x; yf[rg][1] = b0.y; yf[rg][2] = b0.z; yf[rg][3] = b0.w;
          yf[rg][4] = b1.x; yf[rg][5] = b1.y; yf[rg][6] = b1.z; yf[rg][7] = b1.w;
        } else {
#pragma unroll
          for (int j = 0; j < 8; ++j) {
            const int c = cbase + j;
            const bool ok = (unsigned)c < (unsigned)SSIM_W;
            xf[rg][j] = ok ? xr[c] : 0.0f;
            yf[rg][j] = ok ? yr[c] : 0.0f;
          }
        }
      } else {
#pragma unroll
        for (int j = 0; j < 8; ++j) { xf[rg][j] = 0.0f; yf[rg][j] = 0.0f; }
      }
    }
  }

  // Pin the phase boundary: nothing may move across. All 20 dwordx4 issue
  // here; uses below get counted vmcnt waits (rg=0 compute overlaps rg>=1
  // loads in flight). Without this the scheduler re-sinks the loads into
  // the compute loop (observed: VGPR stayed 68, 5 serial round trips).
  __builtin_amdgcn_sched_barrier(0);

  // ---------------- Phase B: L1 + convert + horizontal conv -> Hs ----------
  float l1 = 0.0f;
#pragma unroll
  for (int rg = 0; rg < 5; ++rg) {
    // Exact fp32 L1 on core pixels, counted exactly once:
    // core rows hr in [5,69), core cols k = 8q+j in [5,21).
    const int hr = rg * 16 + m;
    if (hr >= 5 && hr < 69) {
#pragma unroll
      for (int j = 0; j < 8; ++j) {
        const int k = 8 * q + j;
        if (k >= 5 && k < 21) l1 += fabsf(xf[rg][j] - yf[rg][j]);
      }
    }

    half8v ax, ay, axx, ayy, axy;
#pragma unroll
    for (int j = 0; j < 8; ++j) {
      const float x = xf[rg][j], y = yf[rg][j];
      ax[j]  = (_Float16)x;
      ay[j]  = (_Float16)y;
      axx[j] = (_Float16)(x * x);
      ayy[j] = (_Float16)(y * y);
      axy[j] = (_Float16)(x * y);
    }
    const float4v z = {0.0f, 0.0f, 0.0f, 0.0f};
    float4v c0 = __builtin_amdgcn_mfma_f32_16x16x32_f16(ax,  wf, z, 0, 0, 0);
    float4v c1 = __builtin_amdgcn_mfma_f32_16x16x32_f16(ay,  wf, z, 0, 0, 0);
    float4v c2 = __builtin_amdgcn_mfma_f32_16x16x32_f16(axx, wf, z, 0, 0, 0);
    float4v c3 = __builtin_amdgcn_mfma_f32_16x16x32_f16(ayy, wf, z, 0, 0, 0);
    float4v c4 = __builtin_amdgcn_mfma_f32_16x16x32_f16(axy, wf, z, 0, 0, 0);

    // C layout: col=lane&15, row=4q+reg (rows contiguous -> one b64/plane).
    const int hcol = 16 * wv + m;
    const int hrow = rg * 16 + 4 * q;
    half4v h;
    h[0] = (_Float16)c0[0]; h[1] = (_Float16)c0[1];
    h[2] = (_Float16)c0[2]; h[3] = (_Float16)c0[3];
    *(half4v*)&Hs[0][hcol][hrow] = h;
    h[0] = (_Float16)c1[0]; h[1] = (_Float16)c1[1];
    h[2] = (_Float16)c1[2]; h[3] = (_Float16)c1[3];
    *(half4v*)&Hs[1][hcol][hrow] = h;
    h[0] = (_Float16)c2[0]; h[1] = (_Float16)c2[1];
    h[2] = (_Float16)c2[2]; h[3] = (_Float16)c2[3];
    *(half4v*)&Hs[2][hcol][hrow] = h;
    h[0] = (_Float16)c3[0]; h[1] = (_Float16)c3[1];
    h[2] = (_Float16)c3[2]; h[3] = (_Float16)c3[3];
    *(half4v*)&Hs[3][hcol][hrow] = h;
    h[0] = (_Float16)c4[0]; h[1] = (_Float16)c4[1];
    h[2] = (_Float16)c4[2]; h[3] = (_Float16)c4[3];
    *(half4v*)&Hs[4][hcol][hrow] = h;
  }

  // Wave-private LDS dependency: wait for THIS wave's ds_writes only.
  // (Stage 2 reads only the column slab this wave wrote; no cross-wave
  // traffic, so no __syncthreads needed.) sched_barrier after the asm
  // waitcnt per rule #18 (compiler may hoist reg-only ops past asm waits).
  asm volatile("s_waitcnt lgkmcnt(0)" ::: "memory");
  __builtin_amdgcn_sched_barrier(0);

  // ---------------- Stage 2: vertical conv + SSIM (wave-private) ----------
  float ssim = 0.0f;
  {
    const int hcol = 16 * wv + m;  // B-frag col n = lane&15, own slab
    // Issue all 40 ds_read_b64 before any stage-2 MFMA.
    half8v bfr[4][5];
#pragma unroll
    for (int rb = 0; rb < 4; ++rb) {
      const int hrow = 16 * rb + 8 * q;  // window row base (band = rb)
#pragma unroll
      for (int p = 0; p < 5; ++p) {
        const _Float16* hp = &Hs[p][hcol][hrow];
        half4v lo = *(const half4v*)hp;
        half4v hi = *(const half4v*)(hp + 4);
        bfr[rb][p] = __builtin_shufflevector(lo, hi, 0, 1, 2, 3, 4, 5, 6, 7);
      }
    }
    const float C1v = 1.0e-4f, C2v = 9.0e-4f;
#pragma unroll
    for (int rb = 0; rb < 4; ++rb) {
      const float4v z = {0.0f, 0.0f, 0.0f, 0.0f};
      float4v acc[5];
#pragma unroll
      for (int p = 0; p < 5; ++p)
        acc[p] = __builtin_amdgcn_mfma_f32_16x16x32_f16(wf, bfr[rb][p], z,
                                                        0, 0, 0);
#pragma unroll
      for (int r = 0; r < 4; ++r) {
        const float mu1 = acc[0][r], mu2 = acc[1][r];
        const float exx = acc[2][r], eyy = acc[3][r], exy = acc[4][r];
        const float m11 = mu1 * mu1, m22 = mu2 * mu2, m12 = mu1 * mu2;
        const float num = (2.0f * m12 + C1v) * (2.0f * (exy - m12) + C2v);
        const float den = (m11 + m22 + C1v) *
                          ((exx - m11) + (eyy - m22) + C2v);
        ssim += num / den;
      }
    }
  }

  // ---- Reduction: wave shuffle -> LDS -> block -> private partial slot ----
  float v0 = l1, v1 = ssim;
#pragma unroll
  for (int off = 32; off > 0; off >>= 1) {
    v0 += __shfl_down(v0, off, 64);
    v1 += __shfl_down(v1, off, 64);
  }
  if (lane == 0) { red[0][wv] = v0; red[1][wv] = v1; }
  __syncthreads();
  if (tid == 0) {
    d2 s;
    s.x = (double)red[0][0] + (double)red[0][1] +
          (double)red[0][2] + (double)red[0][3];
    s.y = (double)red[1][0] + (double)red[1][1] +
          (double)red[1][2] + (double)red[1][3];
    const int bid = ((int)blockIdx.z * GRID_Y + (int)blockIdx.y) * GRID_X +
                    (int)blockIdx.x;
    *(d2*)(partials + 2 * bid) = s;
  }
}

__global__ __launch_bounds__(256)
void finalize_kernel(const double* __restrict__ partials,
                     float* __restrict__ out) {
  __shared__ double red[2][4];
  const int tid = (int)threadIdx.x;
  double L = 0.0, S = 0.0;
  for (int i = tid; i < TOTAL_BLOCKS; i += 256) {
    const d2 v = *(const d2*)(partials + 2 * i);
    L += v.x;
    S += v.y;
  }
#pragma unroll
  for (int off = 32; off > 0; off >>= 1) {
    L += __shfl_down(L, off, 64);
    S += __shfl_down(S, off, 64);
  }
  const int lane = tid & 63, wid = tid >> 6;
  if (lane == 0) { red[0][wid] = L; red[1][wid] = S; }
  __syncthreads();
  if (tid == 0) {
    const double Ls = red[0][0] + red[0][1] + red[0][2] + red[0][3];
    const double Ss = red[1][0] + red[1][1] + red[1][2] + red[1][3];
    const double invN = 1.0 / N_TOTAL;
    out[0] = (float)(0.84 * (Ls * invN) + 0.16 * (1.0 - Ss * invN));
  }
}

extern "C" void kernel_launch(void* const* d_in, const int* in_sizes, int n_in,
                              void* d_out, int out_size, void* d_ws, size_t ws_size,
                              hipStream_t stream) {
  const float* pred = (const float*)d_in[0];
  const float* targ = (const float*)d_in[1];
  float* out = (float*)d_out;
  double* partials = (double*)d_ws;  // 6144 * 2 doubles = 96 KB

  dim3 grid(GRID_X, GRID_Y, PLANES);  // (8, 8, 96)
  ssim_l1_kernel<<<grid, 256, 0, stream>>>(pred, targ, partials);
  finalize_kernel<<<1, 256, 0, stream>>>(partials, out);
}